// Round 2
// 164.072 us; speedup vs baseline: 1.0478x; 1.0478x over previous
//
#include <hip/hip_runtime.h>
#include <math.h>

#define EPS 1.1920928955078125e-07f   // jnp.finfo(f32).eps

typedef __attribute__((ext_vector_type(8)))  short short8;
typedef __attribute__((ext_vector_type(4)))  short short4v;
typedef __attribute__((ext_vector_type(16))) float floatx16;

__device__ __forceinline__ float4 ld4(const float* __restrict__ p) { return *(const float4* __restrict__)p; }
__device__ __forceinline__ void   st4(float* __restrict__ p, float4 v) { *(float4* __restrict__)p = v; }

// f32 -> bf16 round-to-nearest-even
__device__ __forceinline__ unsigned short f2bf(float f) {
    union { float f; unsigned u; } v; v.f = f;
    unsigned r = v.u + 0x7fffu + ((v.u >> 16) & 1u);
    return (unsigned short)(r >> 16);
}

// ---------------------------------------------------------------------------
// Kernel 1: pack W (MFMA B-frag layout) + embedding->bf16, one launch.
// blocks 0..79: WbF; blocks 80..591: ebf
// ---------------------------------------------------------------------------
__global__ __launch_bounds__(256) void build_pack(const float* __restrict__ val_W,
                                                  const float* __restrict__ key_W,
                                                  const float* __restrict__ emb,
                                                  unsigned short* __restrict__ WbF,
                                                  unsigned short* __restrict__ ebf)
{
    int bid = blockIdx.x;
    if (bid < 80) {
        int idx  = bid * 256 + threadIdx.x;           // 0 .. 20479
        int lane = idx & 63;
        int ks   = (idx >> 6) & 15;
        int nt   = idx >> 10;
        int n = (nt << 5) + (lane & 31);
        int k = (ks << 4) + ((lane >> 5) << 3);
        const float* src = (n < 512) ? key_W + (size_t)n * 256 + k
                                     : val_W + (size_t)(n - 512) * 256 + k;
        float4 v0 = ld4(src), v1 = ld4(src + 4);
        unsigned short o[8] = { f2bf(v0.x), f2bf(v0.y), f2bf(v0.z), f2bf(v0.w),
                                f2bf(v1.x), f2bf(v1.y), f2bf(v1.z), f2bf(v1.w) };
        unsigned short* dst = WbF + (size_t)idx * 8;
        *(short4v*)dst       = *(short4v*)&o[0];
        *(short4v*)(dst + 4) = *(short4v*)&o[4];
    } else {
        int idx = (bid - 80) * 256 + threadIdx.x;     // < 131072
        const float* src = emb + ((size_t)idx << 3);
        float4 v0 = ld4(src), v1 = ld4(src + 4);
        unsigned short o[8] = { f2bf(v0.x), f2bf(v0.y), f2bf(v0.z), f2bf(v0.w),
                                f2bf(v1.x), f2bf(v1.y), f2bf(v1.z), f2bf(v1.w) };
        unsigned short* dst = ebf + ((size_t)idx << 3);
        *(short4v*)dst       = *(short4v*)&o[0];
        *(short4v*)(dst + 4) = *(short4v*)&o[4];
    }
}

// ---------------------------------------------------------------------------
// Kernel 2: hash + gather(bf16) + MFMA GEMM, 32-token tile, ALL 20 n-tiles
// per block (merged parts). grid 1024 = exactly 4 blocks/CU co-resident.
// Per pass s (4 key streams + 1 val): each wave computes ONE 32x32 acc tile
// (acc stays 16 VGPR), D-slab roundtrip, stream epilogue. A staged once.
// ---------------------------------------------------------------------------
__global__ __launch_bounds__(256, 4) void engram_gemm(
    const float* __restrict__ x,
    const int*   __restrict__ input_ids,
    const int*   __restrict__ mult,
    const unsigned short* __restrict__ ebf,
    const float* __restrict__ val_b,
    const float* __restrict__ key_b,
    const float* __restrict__ normq_w,
    const float* __restrict__ normk_w,
    const unsigned short* __restrict__ WbF,
    float* __restrict__ v_base,
    float* __restrict__ Gbuf,
    float* __restrict__ S2buf)
{
    __shared__ int   sids[32][4];
    __shared__ short A[32 * 260];    // bf16 A [32][260], live for all 5 passes
    __shared__ float D[32 * 130];    // f32 D slab [32][130], reused per pass

    const int tid  = threadIdx.x;
    const int tok0 = blockIdx.x << 5;

    if (tid < 32) {
        int token = tok0 + tid;
        int b = token >> 12, t = token & 4095;
        const int* row = input_ids + (b << 12);
        unsigned g2 = (unsigned)row[t];
        unsigned g1 = (t >= 1) ? (unsigned)row[t - 1] : 0u;
        unsigned g0 = (t >= 2) ? (unsigned)row[t - 2] : 0u;
        sids[tid][0] = (int)(((g1 * (unsigned)mult[0]) ^ (g2 * (unsigned)mult[1])) & 4095u);
        sids[tid][1] = (int)((((g1 * (unsigned)mult[3]) ^ (g2 * (unsigned)mult[4])) & 4095u) + 4096u);
        sids[tid][2] = (int)((((g0 * (unsigned)mult[6]) ^ (g1 * (unsigned)mult[7]) ^ (g2 * (unsigned)mult[8])) & 4095u) + 8192u);
        sids[tid][3] = (int)((((g0 * (unsigned)mult[9]) ^ (g1 * (unsigned)mult[10]) ^ (g2 * (unsigned)mult[11])) & 4095u) + 12288u);
    }
    __syncthreads();

    // stage A: 32 tokens x 32 chunks(8 bf16) -> 4 per thread (ONCE per tile)
    #pragma unroll
    for (int it = 0; it < 4; ++it) {
        int f = (it << 8) + tid;
        int token = f >> 5, ch = f & 31;
        const unsigned short* src = ebf + ((size_t)sids[token][ch >> 3] << 6) + ((ch & 7) << 3);
        short4v lo = *(const short4v*)src;
        short4v hi = *(const short4v*)(src + 4);
        short* dst = A + token * 260 + (ch << 3);
        *(short4v*)dst       = lo;
        *(short4v*)(dst + 4) = hi;
    }
    __syncthreads();

    const int lane = tid & 63;
    const int wv   = tid >> 6;
    const int half = lane >> 5;
    const int mrow = lane & 31;

    const short*  Ap = A + mrow * 260 + (half << 3);
    const float4* Bf = (const float4*)WbF + lane;

    const int ty = tid >> 4, tx = tid & 15;
    const int tx8 = tx << 3;
    const int colw = (wv << 5) + mrow;
    const int rb   = half << 2;

    // ---- 4 key-stream passes ----
    for (int s = 0; s < 4; ++s) {
        // x prefetch for this stream: issued before MFMA loop, consumed after
        // two barriers -> HBM latency hides under 16 MFMAs + barriers.
        const float* xp0 = x + ((((size_t)(tok0 + (ty << 1))     << 2) + s) << 7) + tx8;
        const float* xp1 = x + ((((size_t)(tok0 + (ty << 1) + 1) << 2) + s) << 7) + tx8;
        float4 xa0 = ld4(xp0), xb0 = ld4(xp0 + 4);
        float4 xa1 = ld4(xp1), xb1 = ld4(xp1 + 4);

        floatx16 acc;
        #pragma unroll
        for (int r = 0; r < 16; ++r) acc[r] = 0.f;
        const int nt = (s << 2) + wv;
        const float4* bp = Bf + ((size_t)(nt << 4) << 6);
        #pragma unroll 4
        for (int ks = 0; ks < 16; ++ks) {
            short4v al = *(const short4v*)(Ap + (ks << 4));
            short4v ah = *(const short4v*)(Ap + (ks << 4) + 4);
            short8 a = { al[0], al[1], al[2], al[3], ah[0], ah[1], ah[2], ah[3] };
            union { float4 f; short8 s8; } ub;
            ub.f = bp[(size_t)ks << 6];
            acc = __builtin_amdgcn_mfma_f32_32x32x16_bf16(a, ub.s8, acc, 0, 0, 0);
        }

        __syncthreads();
        #pragma unroll
        for (int r = 0; r < 16; ++r) {
            int row = (r & 3) + ((r >> 2) << 3) + rb;
            D[row * 130 + colw] = acc[r];
        }
        __syncthreads();

        const float* kbp = key_b   + (s << 7) + tx8;
        const float* nqp = normq_w + (s << 7) + tx8;
        const float* nkp = normk_w + (s << 7) + tx8;
        float4 kba = ld4(kbp), kbb = ld4(kbp + 4);
        float4 nqa = ld4(nqp), nqb = ld4(nqp + 4);
        float4 nka = ld4(nkp), nkb = ld4(nkp + 4);
        float kb[8] = {kba.x, kba.y, kba.z, kba.w, kbb.x, kbb.y, kbb.z, kbb.w};
        float nq[8] = {nqa.x, nqa.y, nqa.z, nqa.w, nqb.x, nqb.y, nqb.z, nqb.w};
        float nk[8] = {nka.x, nka.y, nka.z, nka.w, nkb.x, nkb.y, nkb.z, nkb.w};
        #pragma unroll
        for (int jj = 0; jj < 2; ++jj) {
            int t_loc = (ty << 1) + jj;
            int token = tok0 + t_loc;
            const float* dp = D + t_loc * 130 + tx8;
            float kr[8]; float ks2 = 0.f;
            #pragma unroll
            for (int m = 0; m < 8; ++m) { kr[m] = dp[m] + kb[m]; ks2 += kr[m] * kr[m]; }
            float xv[8];
            if (jj == 0) { xv[0]=xa0.x; xv[1]=xa0.y; xv[2]=xa0.z; xv[3]=xa0.w;
                           xv[4]=xb0.x; xv[5]=xb0.y; xv[6]=xb0.z; xv[7]=xb0.w; }
            else         { xv[0]=xa1.x; xv[1]=xa1.y; xv[2]=xa1.z; xv[3]=xa1.w;
                           xv[4]=xb1.x; xv[5]=xb1.y; xv[6]=xb1.z; xv[7]=xb1.w; }
            float xs2 = 0.f, dt = 0.f;
            #pragma unroll
            for (int m = 0; m < 8; ++m) { xs2 += xv[m] * xv[m]; dt += xv[m] * nq[m] * kr[m] * nk[m]; }
            #pragma unroll
            for (int off = 1; off < 16; off <<= 1) {
                ks2 += __shfl_xor(ks2, off);
                xs2 += __shfl_xor(xs2, off);
                dt  += __shfl_xor(dt,  off);
            }
            float sc = dt * rsqrtf(xs2 * (1.f / 128.f) + EPS)
                          * rsqrtf(ks2 * (1.f / 128.f) + EPS) * 0.08838834764831845f;
            float gate = 1.f / (1.f + __expf(-sc));
            if (tx == 0) Gbuf[(token << 2) + s] = gate;
        }
    }

    // ---- val pass ----
    {
        floatx16 acc;
        #pragma unroll
        for (int r = 0; r < 16; ++r) acc[r] = 0.f;
        const int nt = 16 + wv;
        const float4* bp = Bf + ((size_t)(nt << 4) << 6);
        #pragma unroll 4
        for (int ks = 0; ks < 16; ++ks) {
            short4v al = *(const short4v*)(Ap + (ks << 4));
            short4v ah = *(const short4v*)(Ap + (ks << 4) + 4);
            short8 a = { al[0], al[1], al[2], al[3], ah[0], ah[1], ah[2], ah[3] };
            union { float4 f; short8 s8; } ub;
            ub.f = bp[(size_t)ks << 6];
            acc = __builtin_amdgcn_mfma_f32_32x32x16_bf16(a, ub.s8, acc, 0, 0, 0);
        }
        __syncthreads();
        #pragma unroll
        for (int r = 0; r < 16; ++r) {
            int row = (r & 3) + ((r >> 2) << 3) + rb;
            D[row * 130 + colw] = acc[r];
        }
        __syncthreads();

        const float* vbp = val_b + tx8;
        float4 vba = ld4(vbp), vbb = ld4(vbp + 4);
        float vb[8] = {vba.x, vba.y, vba.z, vba.w, vbb.x, vbb.y, vbb.z, vbb.w};
        #pragma unroll
        for (int jj = 0; jj < 2; ++jj) {
            int t_loc = (ty << 1) + jj;
            int token = tok0 + t_loc;
            const float* dp = D + t_loc * 130 + tx8;
            float v[8]; float s2 = 0.f;
            #pragma unroll
            for (int m = 0; m < 8; ++m) { v[m] = dp[m] + vb[m]; s2 += v[m] * v[m]; }
            #pragma unroll
            for (int off = 1; off < 16; off <<= 1) s2 += __shfl_xor(s2, off);
            float* vp = v_base + ((size_t)token << 7) + tx8;
            st4(vp,     make_float4(v[0], v[1], v[2], v[3]));
            st4(vp + 4, make_float4(v[4], v[5], v[6], v[7]));
            if (tx == 0) S2buf[token] = s2;
        }
    }
}

// ---------------------------------------------------------------------------
// Kernel 3: gate/xn/conv/SiLU/residual. thread = (4-token group, stream-pair, d4)
// window rows reused across 4 tokens and 2 streams. grid 2048 x 256.
// ---------------------------------------------------------------------------
__global__ __launch_bounds__(256, 4) void engram_out(
    const float* __restrict__ v_base,
    const float* __restrict__ Gbuf,
    const float* __restrict__ S2buf,
    const float* __restrict__ conv_w,
    const float* __restrict__ convnorm_w,
    float* __restrict__ out)
{
    int idx  = blockIdx.x * 256 + threadIdx.x;   // < 524288
    int d4   = idx & 31;
    int sp   = (idx >> 5) & 1;
    int grp  = idx >> 6;                          // 0..8191
    int tg0  = grp << 2;                          // first output token
    int tsq0 = tg0 & 4095;
    int s0   = sp << 1;

    float v[7][4];
    float fw[7][2];
    float gq[4][2];
    #pragma unroll
    for (int j = 0; j < 7; ++j) {
        if (tsq0 + j >= 3) {
            int glob = tg0 - 3 + j;
            float4 vv = ld4(v_base + ((size_t)glob << 7) + (d4 << 2));
            v[j][0] = vv.x; v[j][1] = vv.y; v[j][2] = vv.z; v[j][3] = vv.w;
            float s2n = S2buf[glob] * (1.f / 128.f);
            #pragma unroll
            for (int q = 0; q < 2; ++q) {
                float g = Gbuf[(glob << 2) + s0 + q];
                fw[j][q] = g * rsqrtf(g * g * s2n + EPS);
                if (j >= 3) gq[j - 3][q] = g;
            }
        } else {
            #pragma unroll
            for (int i = 0; i < 4; ++i) v[j][i] = 0.f;
            fw[j][0] = 0.f; fw[j][1] = 0.f;
        }
    }

    float4 w[2][4];
    float  cw[2][4];
    #pragma unroll
    for (int q = 0; q < 2; ++q) {
        float4 c = ld4(convnorm_w + ((s0 + q) << 7) + (d4 << 2));
        cw[q][0] = c.x; cw[q][1] = c.y; cw[q][2] = c.z; cw[q][3] = c.w;
        #pragma unroll
        for (int i = 0; i < 4; ++i)
            w[q][i] = ld4(conv_w + (size_t)(((((s0 + q) << 7) + (d4 << 2) + i)) << 2));
    }

    #pragma unroll
    for (int t = 0; t < 4; ++t) {
        int glob = tg0 + t;
        #pragma unroll
        for (int q = 0; q < 2; ++q) {
            float o[4];
            #pragma unroll
            for (int i = 0; i < 4; ++i) {
                float a = w[q][i].x * v[t][i]     * fw[t][q]
                        + w[q][i].y * v[t + 1][i] * fw[t + 1][q]
                        + w[q][i].z * v[t + 2][i] * fw[t + 2][q]
                        + w[q][i].w * v[t + 3][i] * fw[t + 3][q];
                float y = a * cw[q][i];
                o[i] = v[t + 3][i] * gq[t][q] + y / (1.f + __expf(-y));
            }
            st4(out + ((size_t)((glob << 2) + s0 + q) << 7) + (d4 << 2),
                make_float4(o[0], o[1], o[2], o[3]));
        }
    }
}

// ---------------------------------------------------------------------------
extern "C" void kernel_launch(void* const* d_in, const int* in_sizes, int n_in,
                              void* d_out, int out_size, void* d_ws, size_t ws_size,
                              hipStream_t stream)
{
    const float* x          = (const float*)d_in[0];
    const int*   input_ids  = (const int*)d_in[1];
    const int*   mult       = (const int*)d_in[2];
    const float* embedding  = (const float*)d_in[3];
    const float* val_W      = (const float*)d_in[4];
    const float* val_b      = (const float*)d_in[5];
    const float* key_W      = (const float*)d_in[6];
    const float* key_b      = (const float*)d_in[7];
    const float* normq_w    = (const float*)d_in[8];
    const float* normk_w    = (const float*)d_in[9];
    const float* conv_w     = (const float*)d_in[10];
    const float* convnorm_w = (const float*)d_in[11];
    float* out = (float*)d_out;

    char* ws = (char*)d_ws;
    unsigned short* WbF = (unsigned short*)ws;                    // 327,680 B
    unsigned short* ebf = (unsigned short*)(ws + 327680);         // 2,097,152 B
    float* v_base = (float*)(ws + 327680 + 2097152);              // 16 MiB
    float* Gbuf   = (float*)(ws + 327680 + 2097152 + 16777216);   // 512 KiB
    float* S2buf  = (float*)(ws + 327680 + 2097152 + 16777216 + 524288); // 128 KiB

    build_pack<<<592, 256, 0, stream>>>(val_W, key_W, embedding, WbF, ebf);
    engram_gemm<<<1024, 256, 0, stream>>>(x, input_ids, mult, ebf, val_b, key_b,
                                          normq_w, normk_w, WbF, v_base, Gbuf, S2buf);
    engram_out<<<2048, 256, 0, stream>>>(v_base, Gbuf, S2buf, conv_w, convnorm_w, out);
}